// Round 10
// baseline (151.676 us; speedup 1.0000x reference)
//
#include <hip/hip_runtime.h>

typedef float v2f __attribute__((ext_vector_type(2)));

#define W 1024
#define H 1024
#define NB 16
#define TX 32
#define TY 26               // output rows per block
#define HR 32               // h-conv rows per block = TY + 6
#define NTH 256
#define YBLK ((H + TY - 1) / TY)   // 40 (last block 10 rows OOB, guarded)
#define RSTRIDE (8 * TX)    // dwords per h-row: 8 channels x 32 cols

// ---- forced packed-FP32 (VOP3P). All vector sources must be VGPR pairs;
// scalars are broadcast into a pair once via bc().
__device__ __forceinline__ v2f bc(float b) { v2f r; r.x = b; r.y = b; return r; }
__device__ __forceinline__ v2f pk_mul(v2f a, v2f b) {
    v2f d; asm("v_pk_mul_f32 %0, %1, %2" : "=v"(d) : "v"(a), "v"(b)); return d;
}
__device__ __forceinline__ v2f pk_fma(v2f a, v2f b, v2f c) {
    v2f d; asm("v_pk_fma_f32 %0, %1, %2, %3" : "=v"(d) : "v"(a), "v"(b), "v"(c)); return d;
}
__device__ __forceinline__ v2f pk_add(v2f a, v2f b) {
    v2f d; asm("v_pk_add_f32 %0, %1, %2" : "=v"(d) : "v"(a), "v"(b)); return d;
}

// Vertical conv (TALL outputs) + SSIM map for one column, from LDS.
template <int TALL>
__device__ __forceinline__ float vconv_ssim(
    const float* __restrict__ hbuf, int base, const float* __restrict__ g,
    int gy0 /* image row of output j=0 */)
{
    // hoisted weight broadcast pairs (7 one-time movs)
    v2f gb[7];
    #pragma unroll
    for (int d = 0; d < 7; ++d) gb[d] = bc(g[d]);

    v2f sv[4][TALL];
    #pragma unroll
    for (int cp = 0; cp < 4; ++cp)
        #pragma unroll
        for (int j = 0; j < TALL; ++j) sv[cp][j] = (v2f)0.0f;

    #pragma unroll
    for (int dy = 0; dy < TALL + 6; ++dy) {
        v2f p[4];
        #pragma unroll
        for (int cp = 0; cp < 4; ++cp) {
            p[cp].x = hbuf[base + cp * 64];       // channel 2cp
            p[cp].y = hbuf[base + cp * 64 + 32];  // channel 2cp+1
        }
        #pragma unroll
        for (int j = 0; j < TALL; ++j) {
            const int dd = dy - j;
            if (dd >= 0 && dd < 7) {
                #pragma unroll
                for (int cp = 0; cp < 4; ++cp)
                    sv[cp][j] = pk_fma(p[cp], gb[dd], sv[cp][j]);
            }
        }
        base += RSTRIDE;
    }

    float lsum = 0.0f;
    #pragma unroll
    for (int j = 0; j < TALL; ++j) {
        if (gy0 + j < H) {
            const float mu1 = sv[0][j].x, mu2 = sv[0][j].y;
            const float mu3 = sv[1][j].x, E11 = sv[1][j].y;
            const float E22 = sv[2][j].x, E33 = sv[2][j].y;
            const float E12 = sv[3][j].x, E13 = sv[3][j].y;
            const float sig1  = E11 - mu1 * mu1;
            const float sig2  = E22 - mu2 * mu2;
            const float sig3  = E33 - mu3 * mu3;
            const float sig12 = E12 - mu1 * mu2;
            const float sig13 = E13 - mu1 * mu3;
            const float C2 = 9.0e-4f;  // 0.03^2
            const float m12 = (2.0f * sig12 + C2) * __builtin_amdgcn_rcpf(sig1 + sig2 + C2);
            const float m13 = (2.0f * sig13 + C2) * __builtin_amdgcn_rcpf(sig1 + sig3 + C2);
            lsum += (mu2 > mu3) ? m12 : m13;
        }
    }
    return lsum;
}

// Fused SSIM, packed-FP32 (forced VOP3P), one-shot per block.
//   Stage B: 256 tasks = 32 h-rows x 8 col-groups, one per thread (1:1).
//   Stage C: waves 0-2: 3-tall columns (rows 0..17); wave 3: 4-tall (18..25).
//   LDS exactly 32 KB -> 5 blocks/CU.
__global__ __launch_bounds__(NTH, 5) void ssim_main(
    const float* __restrict__ img1, const float* __restrict__ img2,
    const float* __restrict__ img3, const float* __restrict__ win,
    float* __restrict__ partial)
{
    __shared__ __align__(16) float hbuf[HR * RSTRIDE];  // 32768 B exactly

    const int tid = threadIdx.x;
    const int x0  = blockIdx.x * TX;
    const int ys0 = blockIdx.y * TY;
    const size_t imoff = (size_t)blockIdx.z * (size_t)(W * H);
    const float* p1 = img1 + imoff;
    const float* p2 = img2 + imoff;
    const float* p3 = img3 + imoff;

    // Separable 1-D gaussian: g[j] = win[3][j] / sqrt(win[3][3])
    float g[7];
    {
        const float inv = 1.0f / sqrtf(win[24]);
        #pragma unroll
        for (int j = 0; j < 7; ++j) g[j] = win[21 + j] * inv;
    }

    // ---- Stage B: horizontal conv, global -> LDS (1 task per thread) ----
    {
        const int br  = tid >> 3;            // 0..31  h-row within block
        const int bc0 = (tid & 7) << 2;      // 0,4,...,28
        const int gy  = ys0 + br - 3;
        const int gx0 = x0 + bc0 - 4;
        const bool xfast = (gx0 >= 0) & (gx0 + 12 <= W);

        v2f accA[8], accB[8];                // j=(0,1) and j=(2,3)
        #pragma unroll
        for (int ch = 0; ch < 8; ++ch) { accA[ch] = (v2f)0.0f; accB[ch] = (v2f)0.0f; }

        if ((gy >= 0) & (gy < H)) {
            const size_t rowoff = (size_t)gy * W;
            float V1[12], V2[12], V3[12];
            if (xfast) {
                const float* q1 = p1 + rowoff + gx0;
                const float* q2 = p2 + rowoff + gx0;
                const float* q3 = p3 + rowoff + gx0;
                *(float4*)&V1[0] = *(const float4*)(q1);
                *(float4*)&V1[4] = *(const float4*)(q1 + 4);
                *(float4*)&V1[8] = *(const float4*)(q1 + 8);
                *(float4*)&V2[0] = *(const float4*)(q2);
                *(float4*)&V2[4] = *(const float4*)(q2 + 4);
                *(float4*)&V2[8] = *(const float4*)(q2 + 8);
                *(float4*)&V3[0] = *(const float4*)(q3);
                *(float4*)&V3[4] = *(const float4*)(q3 + 4);
                *(float4*)&V3[8] = *(const float4*)(q3 + 8);
            } else {
                #pragma unroll
                for (int c = 0; c < 12; ++c) {
                    const int x = gx0 + c;
                    const bool ok = (x >= 0) & (x < W);
                    const size_t off = rowoff + x;
                    V1[c] = ok ? p1[off] : 0.0f;
                    V2[c] = ok ? p2[off] : 0.0f;
                    V3[c] = ok ? p3[off] : 0.0f;
                }
            }

            // weight-pair table: gp[m-1] = {g[m-1], g[m-2]} (edges zero-padded)
            v2f gp[8];
            gp[0] = (v2f){g[0], 0.0f};
            #pragma unroll
            for (int m = 2; m <= 7; ++m) gp[m - 1] = (v2f){g[m - 1], g[m - 2]};
            gp[7] = (v2f){0.0f, g[6]};

            #pragma unroll
            for (int m = 1; m <= 8; ++m) {
                const v2f w = gp[m - 1];
                const v2f bA1 = bc(V1[m]), bA2 = bc(V2[m]), bA3 = bc(V3[m]);
                const v2f bB1 = bc(V1[m + 2]), bB2 = bc(V2[m + 2]), bB3 = bc(V3[m + 2]);
                v2f t;
                t = pk_mul(w, bA1);
                accA[0] = pk_add(accA[0], t);
                accA[3] = pk_fma(t, bA1, accA[3]);
                accA[6] = pk_fma(t, bA2, accA[6]);
                accA[7] = pk_fma(t, bA3, accA[7]);
                t = pk_mul(w, bA2);
                accA[1] = pk_add(accA[1], t);
                accA[4] = pk_fma(t, bA2, accA[4]);
                t = pk_mul(w, bA3);
                accA[2] = pk_add(accA[2], t);
                accA[5] = pk_fma(t, bA3, accA[5]);
                t = pk_mul(w, bB1);
                accB[0] = pk_add(accB[0], t);
                accB[3] = pk_fma(t, bB1, accB[3]);
                accB[6] = pk_fma(t, bB2, accB[6]);
                accB[7] = pk_fma(t, bB3, accB[7]);
                t = pk_mul(w, bB2);
                accB[1] = pk_add(accB[1], t);
                accB[4] = pk_fma(t, bB2, accB[4]);
                t = pk_mul(w, bB3);
                accB[2] = pk_add(accB[2], t);
                accB[5] = pk_fma(t, bB3, accB[5]);
            }
        }
        const int wbase = br * RSTRIDE + bc0;
        #pragma unroll
        for (int ch = 0; ch < 8; ++ch) {
            *(v2f*)&hbuf[wbase + ch * TX]     = accA[ch];
            *(v2f*)&hbuf[wbase + ch * TX + 2] = accB[ch];
        }
    }
    __syncthreads();

    // ---- Stage C: vertical conv + SSIM (3-tall waves 0-2, 4-tall wave 3) ----
    const int tx = tid & 31;
    float lsum;
    if (tid < 192) {
        const int r0 = (tid >> 5) * 3;           // 0,3,...,15
        lsum = vconv_ssim<3>(hbuf, r0 * RSTRIDE + tx, g, ys0 + r0);
    } else {
        const int r0 = 18 + (((tid >> 5) - 6) << 2);  // 18, 22
        lsum = vconv_ssim<4>(hbuf, r0 * RSTRIDE + tx, g, ys0 + r0);
    }

    // ---- Block reduction (deterministic); alias wavesum onto hbuf ----
    #pragma unroll
    for (int o = 32; o > 0; o >>= 1) lsum += __shfl_down(lsum, o, 64);
    __syncthreads();                      // all hbuf reads done before aliasing
    float* wavesum = hbuf;
    if ((tid & 63) == 0) wavesum[tid >> 6] = lsum;
    __syncthreads();
    if (tid == 0) {
        const float t = (wavesum[0] + wavesum[1]) + (wavesum[2] + wavesum[3]);
        partial[((size_t)blockIdx.z * gridDim.y + blockIdx.y) * gridDim.x + blockIdx.x] = t;
    }
}

// Deterministic final reduction: one block, fixed summation order, f64 accum.
__global__ __launch_bounds__(256) void ssim_reduce(
    const float* __restrict__ partial, float* __restrict__ out, int n)
{
    __shared__ double sh[256];
    const int tid = threadIdx.x;
    double s = 0.0;
    for (int i = tid; i < n; i += 256) s += (double)partial[i];
    sh[tid] = s;
    __syncthreads();
    for (int o = 128; o > 0; o >>= 1) {
        if (tid < o) sh[tid] += sh[tid + o];
        __syncthreads();
    }
    if (tid == 0) out[0] = (float)(sh[0] / (double)((size_t)NB * W * H));
}

extern "C" void kernel_launch(void* const* d_in, const int* in_sizes, int n_in,
                              void* d_out, int out_size, void* d_ws, size_t ws_size,
                              hipStream_t stream) {
    const float* img1 = (const float*)d_in[0];
    const float* img2 = (const float*)d_in[1];
    const float* img3 = (const float*)d_in[2];
    const float* win  = (const float*)d_in[3];
    float* out = (float*)d_out;
    float* partial = (float*)d_ws;

    dim3 grid(W / TX, YBLK, NB);  // 32 x 40 x 16 = 20480 blocks
    ssim_main<<<grid, NTH, 0, stream>>>(img1, img2, img3, win, partial);

    const int nblk = (W / TX) * YBLK * NB;
    ssim_reduce<<<1, 256, 0, stream>>>(partial, out, nblk);
}

// Round 11
// 122.715 us; speedup vs baseline: 1.2360x; 1.2360x over previous
//
#include <hip/hip_runtime.h>

typedef float v2f __attribute__((ext_vector_type(2)));

#define W 1024
#define H 1024
#define NB 16
#define TX 32
#define TY 26               // output rows per block
#define HR 32               // h-conv rows per block = TY + 6
#define NTH 256
#define YBLK ((H + TY - 1) / TY)   // 40 (last block 10 rows OOB, guarded)
#define RSTRIDE (4 * TX * 2) // dwords per h-row: 4 chpairs x 32 cols x 2
// hbuf layout: [row][cp][col][2]  (pair = channels 2cp, 2cp+1 interleaved)
// -> stage C reads one v2f (ds_read_b64) per chpair: packed operand = load dest.

// Vertical conv (TALL outputs) + SSIM map for one column, from LDS.
template <int TALL>
__device__ __forceinline__ float vconv_ssim(
    const float* __restrict__ hbuf, int base, const float* __restrict__ g,
    int gy0 /* image row of output j=0 */)
{
    v2f sv[4][TALL];
    #pragma unroll
    for (int cp = 0; cp < 4; ++cp)
        #pragma unroll
        for (int j = 0; j < TALL; ++j) sv[cp][j] = (v2f)0.0f;

    #pragma unroll
    for (int dy = 0; dy < TALL + 6; ++dy) {
        v2f p[4];
        #pragma unroll
        for (int cp = 0; cp < 4; ++cp)
            p[cp] = *(const v2f*)&hbuf[base + dy * RSTRIDE + cp * 64];
        #pragma unroll
        for (int j = 0; j < TALL; ++j) {
            const int dd = dy - j;
            if (dd >= 0 && dd < 7) {
                const float wg = g[dd];
                #pragma unroll
                for (int cp = 0; cp < 4; ++cp) sv[cp][j] += wg * p[cp];
            }
        }
    }

    float lsum = 0.0f;
    #pragma unroll
    for (int j = 0; j < TALL; ++j) {
        if (gy0 + j < H) {
            const float mu1 = sv[0][j].x, mu2 = sv[0][j].y;
            const float mu3 = sv[1][j].x, E11 = sv[1][j].y;
            const float E22 = sv[2][j].x, E33 = sv[2][j].y;
            const float E12 = sv[3][j].x, E13 = sv[3][j].y;
            const float sig1  = E11 - mu1 * mu1;
            const float sig2  = E22 - mu2 * mu2;
            const float sig3  = E33 - mu3 * mu3;
            const float sig12 = E12 - mu1 * mu2;
            const float sig13 = E13 - mu1 * mu3;
            const float C2 = 9.0e-4f;  // 0.03^2
            const float m12 = (2.0f * sig12 + C2) * __builtin_amdgcn_rcpf(sig1 + sig2 + C2);
            const float m13 = (2.0f * sig13 + C2) * __builtin_amdgcn_rcpf(sig1 + sig3 + C2);
            lsum += (mu2 > mu3) ? m12 : m13;
        }
    }
    return lsum;
}

// Fused SSIM, packed-FP32 via pair-interleaved LDS, one-shot per block.
//   Stage B: 256 tasks = 32 h-rows x 8 col-groups, one per thread (1:1).
//   Stage C: waves 0-2: 3-tall columns (rows 0..17); wave 3: 4-tall (18..25).
//   LDS exactly 32 KB -> 5 blocks/CU.
__global__ __launch_bounds__(NTH, 4) void ssim_main(
    const float* __restrict__ img1, const float* __restrict__ img2,
    const float* __restrict__ img3, const float* __restrict__ win,
    float* __restrict__ partial)
{
    __shared__ __align__(16) float hbuf[HR * RSTRIDE];  // 32768 B exactly

    const int tid = threadIdx.x;
    const int x0  = blockIdx.x * TX;
    const int ys0 = blockIdx.y * TY;
    const size_t imoff = (size_t)blockIdx.z * (size_t)(W * H);
    const float* p1 = img1 + imoff;
    const float* p2 = img2 + imoff;
    const float* p3 = img3 + imoff;

    // Separable 1-D gaussian: g[j] = win[3][j] / sqrt(win[3][3])
    float g[7];
    {
        const float inv = 1.0f / sqrtf(win[24]);
        #pragma unroll
        for (int j = 0; j < 7; ++j) g[j] = win[21 + j] * inv;
    }

    // ---- Stage B: horizontal conv, global -> LDS (1 task per thread) ----
    {
        const int br  = tid >> 3;            // 0..31  h-row within block
        const int bc0 = (tid & 7) << 2;      // 0,4,...,28
        const int gy  = ys0 + br - 3;
        const int gx0 = x0 + bc0 - 4;
        const bool xfast = (gx0 >= 0) & (gx0 + 12 <= W);

        v2f accA[8], accB[8];                // cols j=(0,1) and j=(2,3) per channel
        #pragma unroll
        for (int ch = 0; ch < 8; ++ch) { accA[ch] = (v2f)0.0f; accB[ch] = (v2f)0.0f; }

        if ((gy >= 0) & (gy < H)) {
            const size_t rowoff = (size_t)gy * W;
            float V1[12], V2[12], V3[12];
            if (xfast) {
                const float* q1 = p1 + rowoff + gx0;
                const float* q2 = p2 + rowoff + gx0;
                const float* q3 = p3 + rowoff + gx0;
                *(float4*)&V1[0] = *(const float4*)(q1);
                *(float4*)&V1[4] = *(const float4*)(q1 + 4);
                *(float4*)&V1[8] = *(const float4*)(q1 + 8);
                *(float4*)&V2[0] = *(const float4*)(q2);
                *(float4*)&V2[4] = *(const float4*)(q2 + 4);
                *(float4*)&V2[8] = *(const float4*)(q2 + 8);
                *(float4*)&V3[0] = *(const float4*)(q3);
                *(float4*)&V3[4] = *(const float4*)(q3 + 4);
                *(float4*)&V3[8] = *(const float4*)(q3 + 8);
            } else {
                #pragma unroll
                for (int c = 0; c < 12; ++c) {
                    const int x = gx0 + c;
                    const bool ok = (x >= 0) & (x < W);
                    const size_t off = rowoff + x;
                    V1[c] = ok ? p1[off] : 0.0f;
                    V2[c] = ok ? p2[off] : 0.0f;
                    V3[c] = ok ? p3[off] : 0.0f;
                }
            }

            // weight-pair table: gp[m-1] = {g[m-1], g[m-2]} (edges zero-padded)
            v2f gp[8];
            gp[0] = (v2f){g[0], 0.0f};
            #pragma unroll
            for (int m = 2; m <= 7; ++m) gp[m - 1] = (v2f){g[m - 1], g[m - 2]};
            gp[7] = (v2f){0.0f, g[6]};

            #pragma unroll
            for (int m = 1; m <= 8; ++m) {
                const v2f w = gp[m - 1];
                const float vA1 = V1[m], vA2 = V2[m], vA3 = V3[m];
                const float vB1 = V1[m + 2], vB2 = V2[m + 2], vB3 = V3[m + 2];
                v2f t;
                t = w * vA1;
                accA[0] += t;
                accA[3] += t * vA1;
                accA[6] += t * vA2;
                accA[7] += t * vA3;
                t = w * vA2;
                accA[1] += t;
                accA[4] += t * vA2;
                t = w * vA3;
                accA[2] += t;
                accA[5] += t * vA3;
                t = w * vB1;
                accB[0] += t;
                accB[3] += t * vB1;
                accB[6] += t * vB2;
                accB[7] += t * vB3;
                t = w * vB2;
                accB[1] += t;
                accB[4] += t * vB2;
                t = w * vB3;
                accB[2] += t;
                accB[5] += t * vB3;
            }
        }
        // pair-interleaved write: [row][cp][col][2], 16x ds_write_b64
        const int wbase = br * RSTRIDE + bc0 * 2;
        #pragma unroll
        for (int cp = 0; cp < 4; ++cp) {
            float* d = &hbuf[wbase + cp * 64];
            v2f q;
            q.x = accA[2 * cp].x; q.y = accA[2 * cp + 1].x; *(v2f*)(d + 0) = q;
            q.x = accA[2 * cp].y; q.y = accA[2 * cp + 1].y; *(v2f*)(d + 2) = q;
            q.x = accB[2 * cp].x; q.y = accB[2 * cp + 1].x; *(v2f*)(d + 4) = q;
            q.x = accB[2 * cp].y; q.y = accB[2 * cp + 1].y; *(v2f*)(d + 6) = q;
        }
    }
    __syncthreads();

    // ---- Stage C: vertical conv + SSIM (3-tall waves 0-2, 4-tall wave 3) ----
    const int tx = tid & 31;
    float lsum;
    if (tid < 192) {
        const int r0 = (tid >> 5) * 3;           // 0,3,...,15
        lsum = vconv_ssim<3>(hbuf, r0 * RSTRIDE + tx * 2, g, ys0 + r0);
    } else {
        const int r0 = 18 + (((tid >> 5) - 6) << 2);  // 18, 22
        lsum = vconv_ssim<4>(hbuf, r0 * RSTRIDE + tx * 2, g, ys0 + r0);
    }

    // ---- Block reduction (deterministic); alias wavesum onto hbuf ----
    #pragma unroll
    for (int o = 32; o > 0; o >>= 1) lsum += __shfl_down(lsum, o, 64);
    __syncthreads();                      // all hbuf reads done before aliasing
    float* wavesum = hbuf;
    if ((tid & 63) == 0) wavesum[tid >> 6] = lsum;
    __syncthreads();
    if (tid == 0) {
        const float t = (wavesum[0] + wavesum[1]) + (wavesum[2] + wavesum[3]);
        partial[((size_t)blockIdx.z * gridDim.y + blockIdx.y) * gridDim.x + blockIdx.x] = t;
    }
}

// Deterministic final reduction: one block, fixed summation order, f64 accum.
__global__ __launch_bounds__(256) void ssim_reduce(
    const float* __restrict__ partial, float* __restrict__ out, int n)
{
    __shared__ double sh[256];
    const int tid = threadIdx.x;
    double s = 0.0;
    for (int i = tid; i < n; i += 256) s += (double)partial[i];
    sh[tid] = s;
    __syncthreads();
    for (int o = 128; o > 0; o >>= 1) {
        if (tid < o) sh[tid] += sh[tid + o];
        __syncthreads();
    }
    if (tid == 0) out[0] = (float)(sh[0] / (double)((size_t)NB * W * H));
}

extern "C" void kernel_launch(void* const* d_in, const int* in_sizes, int n_in,
                              void* d_out, int out_size, void* d_ws, size_t ws_size,
                              hipStream_t stream) {
    const float* img1 = (const float*)d_in[0];
    const float* img2 = (const float*)d_in[1];
    const float* img3 = (const float*)d_in[2];
    const float* win  = (const float*)d_in[3];
    float* out = (float*)d_out;
    float* partial = (float*)d_ws;

    dim3 grid(W / TX, YBLK, NB);  // 32 x 40 x 16 = 20480 blocks
    ssim_main<<<grid, NTH, 0, stream>>>(img1, img2, img3, win, partial);

    const int nblk = (W / TX) * YBLK * NB;
    ssim_reduce<<<1, 256, 0, stream>>>(partial, out, nblk);
}